// Round 3
// baseline (182.182 us; speedup 1.0000x reference)
//
#include <hip/hip_runtime.h>
#include <hip/hip_bf16.h>
#include <cstdint>

#define V_N    50000
#define C_N    128
#define COUT_N 256
#define DEG_N  16
#define K2_N   256   // 2*C

typedef short bf16x8 __attribute__((ext_vector_type(8)));
typedef float f32x4  __attribute__((ext_vector_type(4)));

__device__ __forceinline__ unsigned short f2bf(float f) {
    union { float f; unsigned u; } a; a.f = f;
    unsigned r = a.u + 0x7fffu + ((a.u >> 16) & 1u);   // round-to-nearest-even
    return (unsigned short)(r >> 16);
}
__device__ __forceinline__ float bflo(unsigned p) {
    union { unsigned u; float f; } a; a.u = p << 16; return a.f;
}
__device__ __forceinline__ float bfhi(unsigned p) {
    union { unsigned u; float f; } a; a.u = p & 0xffff0000u; return a.f;
}

// Kernel weights -> bf16, pre-swizzled into MFMA B-fragment order:
// element (n,k) -> bt[ ((nb*8+ks)*4+kk)*128 + nr*8 + kp ]
//   nb=n>>4, nr=n&15, ks=k>>5, kk=(k>>3)&3, kp=k&7
// so a (nf,ks) fragment load is lane-linear 16B -> one coalesced 1KB instr.
__global__ void prep_bt_kernel(const float* __restrict__ kern,
                               unsigned short* __restrict__ bt) {
    const int k = blockIdx.x;    // 0..255
    const int n = threadIdx.x;   // 0..255
    const int idx = (((n >> 4) * 8 + (k >> 5)) * 4 + ((k >> 3) & 3)) * 128
                  + (n & 15) * 8 + (k & 7);
    bt[idx] = f2bf(kern[k * COUT_N + n]);
}

// Convert data fp32 -> bf16 table (halves gather bytes). 12.8MB in d_ws.
__global__ __launch_bounds__(256)
void prep_data_kernel(const float* __restrict__ data,
                      unsigned short* __restrict__ db) {
    const int i = blockIdx.x * 256 + threadIdx.x;        // unit of 8 floats; grid exact
    const float4 f0 = *reinterpret_cast<const float4*>(data + (size_t)i * 8);
    const float4 f1 = *reinterpret_cast<const float4*>(data + (size_t)i * 8 + 4);
    union { unsigned short h[8]; uint4 q; } o;
    o.h[0] = f2bf(f0.x); o.h[1] = f2bf(f0.y); o.h[2] = f2bf(f0.z); o.h[3] = f2bf(f0.w);
    o.h[4] = f2bf(f1.x); o.h[5] = f2bf(f1.y); o.h[6] = f2bf(f1.z); o.h[7] = f2bf(f1.w);
    *reinterpret_cast<uint4*>(db + (size_t)i * 8) = o.q;
}

// Fused: quad-gather weighted aggregation -> bf16 A tile in LDS -> single-pass MFMA.
// 512 threads (8 waves), BM = 64 vertices. LDS = A tile 64x512B = 32KB, XOR-swizzled.
// Phase 1: each wave aggregates 8 vertices as 2 quads; a 16-lane group owns one
// vertex; one gather instr = 4 rows x 256B = 1KB, fully coalesced.
// Phase 2: 8 waves tile 64x256 output (wm: 2x32 rows, wn: 4x64 cols), B-frags
// from pre-swizzled global Bt (lane-linear), K=256 in 8 MFMA steps.
__global__ __launch_bounds__(512, 6)
void dgc_fused_kernel(const unsigned short* __restrict__ db,
                      const int* __restrict__ edge_dst,
                      const float* __restrict__ edge_w,
                      const unsigned short* __restrict__ btg,
                      const float* __restrict__ bias,
                      float* __restrict__ out) {
    __shared__ __align__(16) char Asm[64 * 512];   // 32KB

    const int tid  = threadIdx.x;
    const int lane = tid & 63;
    const int wid  = __builtin_amdgcn_readfirstlane(tid >> 6);  // 0..7
    const int m0   = blockIdx.x * 64;
    const int g    = lane >> 4;     // quad-group / k-slice index
    const int c    = lane & 15;     // 16B chunk index

    // ---------------- Phase 1: aggregate 64 vertices ----------------
    #pragma unroll
    for (int q = 0; q < 2; ++q) {
        const int row = wid * 8 + q * 4 + g;     // 0..63
        const int vq  = m0 + row;
        float s[8];
        #pragma unroll
        for (int i = 0; i < 8; ++i) s[i] = 0.f;
        float Wsum = 0.f;
        uint4 xr = make_uint4(0u, 0u, 0u, 0u);
        if (vq < V_N) {
            xr = *reinterpret_cast<const uint4*>(db + (size_t)vq * C_N + c * 8);
            const int eb = vq * DEG_N;
            #pragma unroll
            for (int k = 0; k < DEG_N; ++k) {
                const int   j  = edge_dst[eb + k];   // 16 lanes same addr -> broadcast
                const float wk = edge_w[eb + k];
                const uint4 r  = *reinterpret_cast<const uint4*>(
                    db + (size_t)j * C_N + c * 8);   // 1KB/wave, coalesced
                s[0] = fmaf(wk, bflo(r.x), s[0]);
                s[1] = fmaf(wk, bfhi(r.x), s[1]);
                s[2] = fmaf(wk, bflo(r.y), s[2]);
                s[3] = fmaf(wk, bfhi(r.y), s[3]);
                s[4] = fmaf(wk, bflo(r.z), s[4]);
                s[5] = fmaf(wk, bfhi(r.z), s[5]);
                s[6] = fmaf(wk, bflo(r.w), s[6]);
                s[7] = fmaf(wk, bfhi(r.w), s[7]);
                Wsum += wk;
            }
        }
        float u[8], v[8];
        u[0] = Wsum * bflo(xr.x); u[1] = Wsum * bfhi(xr.x);
        u[2] = Wsum * bflo(xr.y); u[3] = Wsum * bfhi(xr.y);
        u[4] = Wsum * bflo(xr.z); u[5] = Wsum * bfhi(xr.z);
        u[6] = Wsum * bflo(xr.w); u[7] = Wsum * bfhi(xr.w);
        #pragma unroll
        for (int i = 0; i < 8; ++i) v[i] = s[i] - u[i];

        uint4 up, vp;
        up.x = (unsigned)f2bf(u[0]) | ((unsigned)f2bf(u[1]) << 16);
        up.y = (unsigned)f2bf(u[2]) | ((unsigned)f2bf(u[3]) << 16);
        up.z = (unsigned)f2bf(u[4]) | ((unsigned)f2bf(u[5]) << 16);
        up.w = (unsigned)f2bf(u[6]) | ((unsigned)f2bf(u[7]) << 16);
        vp.x = (unsigned)f2bf(v[0]) | ((unsigned)f2bf(v[1]) << 16);
        vp.y = (unsigned)f2bf(v[2]) | ((unsigned)f2bf(v[3]) << 16);
        vp.z = (unsigned)f2bf(v[4]) | ((unsigned)f2bf(v[5]) << 16);
        vp.w = (unsigned)f2bf(v[6]) | ((unsigned)f2bf(v[7]) << 16);

        // A row: k<128 -> u=W*x ; k>=128 -> v=s-W*x. 32x16B chunks, chunk ^= row&7.
        const int sw   = row & 7;
        char*     rowp = Asm + row * 512;
        *reinterpret_cast<uint4*>(rowp + ((c        ^ sw) * 16)) = up;
        *reinterpret_cast<uint4*>(rowp + (((16 + c) ^ sw) * 16)) = vp;
    }
    __syncthreads();

    // ---------------- Phase 2: A[64x256] @ K[256x256] ----------------
    const int wm = wid >> 2;   // 0..1 : 32-row wave tile
    const int wn = wid & 3;    // 0..3 : 64-col wave tile

    f32x4 acc[2][4];
    #pragma unroll
    for (int mf = 0; mf < 2; ++mf)
        #pragma unroll
        for (int nf = 0; nf < 4; ++nf)
            acc[mf][nf] = (f32x4){0.f, 0.f, 0.f, 0.f};

    #pragma unroll
    for (int ks = 0; ks < 8; ++ks) {     // K = 256 = 8 * 32
        bf16x8 a[2], b[4];
        #pragma unroll
        for (int mf = 0; mf < 2; ++mf) {
            const int r  = wm * 32 + mf * 16 + c;
            const int ck = (ks * 4 + g) ^ (r & 7);
            a[mf] = *reinterpret_cast<const bf16x8*>(Asm + r * 512 + ck * 16);
        }
        #pragma unroll
        for (int nf = 0; nf < 4; ++nf) {
            const int nb = wn * 4 + nf;
            b[nf] = *reinterpret_cast<const bf16x8*>(
                btg + (size_t)((nb * 32 + ks * 4 + g) * 16 + c) * 8);  // lane-linear 1KB
        }
        #pragma unroll
        for (int mf = 0; mf < 2; ++mf)
            #pragma unroll
            for (int nf = 0; nf < 4; ++nf)
                acc[mf][nf] = __builtin_amdgcn_mfma_f32_16x16x32_bf16(
                    a[mf], b[nf], acc[mf][nf], 0, 0, 0);
    }

    // Epilogue: C/D layout col = lane&15, row = (lane>>4)*4 + reg. bias ok (Σw==1).
    #pragma unroll
    for (int mf = 0; mf < 2; ++mf) {
        const int row_l = wm * 32 + mf * 16 + g * 4;
        #pragma unroll
        for (int nf = 0; nf < 4; ++nf) {
            const int col = wn * 64 + nf * 16 + c;
            const float bb = bias[col];
            #pragma unroll
            for (int r = 0; r < 4; ++r) {
                const int rg = m0 + row_l + r;
                if (rg < V_N)
                    out[(size_t)rg * COUT_N + col] = acc[mf][nf][r] + bb;
            }
        }
    }
}

extern "C" void kernel_launch(void* const* d_in, const int* in_sizes, int n_in,
                              void* d_out, int out_size, void* d_ws, size_t ws_size,
                              hipStream_t stream) {
    const float* data     = (const float*)d_in[0];
    // d_in[1] = edge_src: implicit (vertex i owns edges [16i,16i+16)), unused
    const int*   edge_dst = (const int*)d_in[2];
    const float* edge_w   = (const float*)d_in[3];
    const float* kern     = (const float*)d_in[4];
    const float* bias     = (const float*)d_in[5];
    float*       out      = (float*)d_out;

    unsigned short* bt = (unsigned short*)d_ws;                          // 128KB
    unsigned short* db = (unsigned short*)d_ws + (size_t)K2_N * COUT_N;  // 12.8MB

    prep_bt_kernel<<<K2_N, COUT_N, 0, stream>>>(kern, bt);
    prep_data_kernel<<<(V_N * C_N / 8) / 256, 256, 0, stream>>>(data, db);

    const int nblk = (V_N + 63) / 64;   // 782
    dgc_fused_kernel<<<nblk, 512, 0, stream>>>(db, edge_dst, edge_w, bt, bias, out);
}

// Round 4
// 141.697 us; speedup vs baseline: 1.2857x; 1.2857x over previous
//
#include <hip/hip_runtime.h>
#include <hip/hip_bf16.h>
#include <cstdint>

#define V_N    50000
#define C_N    128
#define COUT_N 256
#define DEG_N  16
#define K2_N   256   // 2*C

typedef short bf16x8 __attribute__((ext_vector_type(8)));
typedef float f32x4  __attribute__((ext_vector_type(4)));

__device__ __forceinline__ unsigned short f2bf(float f) {
    union { float f; unsigned u; } a; a.f = f;
    unsigned r = a.u + 0x7fffu + ((a.u >> 16) & 1u);   // round-to-nearest-even
    return (unsigned short)(r >> 16);
}
__device__ __forceinline__ float bflo(unsigned p) {
    union { unsigned u; float f; } a; a.u = p << 16; return a.f;
}
__device__ __forceinline__ float bfhi(unsigned p) {
    union { unsigned u; float f; } a; a.u = p & 0xffff0000u; return a.f;
}

// Kernel weights -> bf16, pre-swizzled into MFMA B-fragment order:
// element (n,k) -> bt[ ((nb*8+ks)*4+kk)*128 + nr*8 + kp ]
//   nb=n>>4, nr=n&15, ks=k>>5, kk=(k>>3)&3, kp=k&7
// so a (nf,ks) fragment load is lane-linear 16B -> one coalesced 1KB instr.
__global__ void prep_bt_kernel(const float* __restrict__ kern,
                               unsigned short* __restrict__ bt) {
    const int k = blockIdx.x;    // 0..255
    const int n = threadIdx.x;   // 0..255
    const int idx = (((n >> 4) * 8 + (k >> 5)) * 4 + ((k >> 3) & 3)) * 128
                  + (n & 15) * 8 + (k & 7);
    bt[idx] = f2bf(kern[k * COUT_N + n]);
}

// Convert data fp32 -> bf16 table (halves gather bytes). 12.8MB in d_ws.
__global__ __launch_bounds__(256)
void prep_data_kernel(const float* __restrict__ data,
                      unsigned short* __restrict__ db) {
    const int i = blockIdx.x * 256 + threadIdx.x;        // unit of 8 floats; grid exact
    const float4 f0 = *reinterpret_cast<const float4*>(data + (size_t)i * 8);
    const float4 f1 = *reinterpret_cast<const float4*>(data + (size_t)i * 8 + 4);
    union { unsigned short h[8]; uint4 q; } o;
    o.h[0] = f2bf(f0.x); o.h[1] = f2bf(f0.y); o.h[2] = f2bf(f0.z); o.h[3] = f2bf(f0.w);
    o.h[4] = f2bf(f1.x); o.h[5] = f2bf(f1.y); o.h[6] = f2bf(f1.z); o.h[7] = f2bf(f1.w);
    *reinterpret_cast<uint4*>(db + (size_t)i * 8) = o.q;
}

// Fused: quad-gather weighted aggregation -> bf16 A tile in LDS -> single-pass MFMA.
// 512 threads (8 waves), BM = 64 vertices. LDS = A tile 64x512B = 32KB, XOR-swizzled.
// Phase 1: each wave aggregates 8 vertices as 2 quads; a 16-lane group owns one
// vertex; one gather instr = 4 rows x 256B = 1KB, fully coalesced.
// Phase 2: 8 waves tile 64x256 output (wm: 2x32 rows, wn: 4x64 cols), B-frags
// from pre-swizzled global Bt (lane-linear), K=256 in 8 MFMA steps.
//
// launch_bounds note: (512,6) in round 3 capped VGPR at 85, allocator squeezed
// to 40 and SPILLED -> +180MB scratch HBM traffic, 95us. (512,4) = 128-reg cap,
// no spill, 2 blocks/CU (16 waves/CU) — grid (782/256CU) limits occupancy anyway.
__global__ __launch_bounds__(512, 4)
void dgc_fused_kernel(const unsigned short* __restrict__ db,
                      const int* __restrict__ edge_dst,
                      const float* __restrict__ edge_w,
                      const unsigned short* __restrict__ btg,
                      const float* __restrict__ bias,
                      float* __restrict__ out) {
    __shared__ __align__(16) char Asm[64 * 512];   // 32KB

    const int tid  = threadIdx.x;
    const int lane = tid & 63;
    const int wid  = __builtin_amdgcn_readfirstlane(tid >> 6);  // 0..7
    const int m0   = blockIdx.x * 64;
    const int g    = lane >> 4;     // quad-group / k-slice index
    const int c    = lane & 15;     // 16B chunk index

    // ---------------- Phase 1: aggregate 64 vertices ----------------
    #pragma unroll
    for (int q = 0; q < 2; ++q) {
        const int row = wid * 8 + q * 4 + g;     // 0..63
        const int vq  = m0 + row;
        float s[8];
        #pragma unroll
        for (int i = 0; i < 8; ++i) s[i] = 0.f;
        float Wsum = 0.f;
        uint4 xr = make_uint4(0u, 0u, 0u, 0u);
        if (vq < V_N) {
            xr = *reinterpret_cast<const uint4*>(db + (size_t)vq * C_N + c * 8);
            const int eb = vq * DEG_N;
            #pragma unroll
            for (int k = 0; k < DEG_N; ++k) {
                const int   j  = edge_dst[eb + k];   // 16 lanes same addr -> broadcast
                const float wk = edge_w[eb + k];
                const uint4 r  = *reinterpret_cast<const uint4*>(
                    db + (size_t)j * C_N + c * 8);   // 1KB/wave, coalesced
                s[0] = fmaf(wk, bflo(r.x), s[0]);
                s[1] = fmaf(wk, bfhi(r.x), s[1]);
                s[2] = fmaf(wk, bflo(r.y), s[2]);
                s[3] = fmaf(wk, bfhi(r.y), s[3]);
                s[4] = fmaf(wk, bflo(r.z), s[4]);
                s[5] = fmaf(wk, bfhi(r.z), s[5]);
                s[6] = fmaf(wk, bflo(r.w), s[6]);
                s[7] = fmaf(wk, bfhi(r.w), s[7]);
                Wsum += wk;
            }
        }
        float u[8], v[8];
        u[0] = Wsum * bflo(xr.x); u[1] = Wsum * bfhi(xr.x);
        u[2] = Wsum * bflo(xr.y); u[3] = Wsum * bfhi(xr.y);
        u[4] = Wsum * bflo(xr.z); u[5] = Wsum * bfhi(xr.z);
        u[6] = Wsum * bflo(xr.w); u[7] = Wsum * bfhi(xr.w);
        #pragma unroll
        for (int i = 0; i < 8; ++i) v[i] = s[i] - u[i];

        uint4 up, vp;
        up.x = (unsigned)f2bf(u[0]) | ((unsigned)f2bf(u[1]) << 16);
        up.y = (unsigned)f2bf(u[2]) | ((unsigned)f2bf(u[3]) << 16);
        up.z = (unsigned)f2bf(u[4]) | ((unsigned)f2bf(u[5]) << 16);
        up.w = (unsigned)f2bf(u[6]) | ((unsigned)f2bf(u[7]) << 16);
        vp.x = (unsigned)f2bf(v[0]) | ((unsigned)f2bf(v[1]) << 16);
        vp.y = (unsigned)f2bf(v[2]) | ((unsigned)f2bf(v[3]) << 16);
        vp.z = (unsigned)f2bf(v[4]) | ((unsigned)f2bf(v[5]) << 16);
        vp.w = (unsigned)f2bf(v[6]) | ((unsigned)f2bf(v[7]) << 16);

        // A row: k<128 -> u=W*x ; k>=128 -> v=s-W*x. 32x16B chunks, chunk ^= row&7.
        const int sw   = row & 7;
        char*     rowp = Asm + row * 512;
        *reinterpret_cast<uint4*>(rowp + ((c        ^ sw) * 16)) = up;
        *reinterpret_cast<uint4*>(rowp + (((16 + c) ^ sw) * 16)) = vp;
    }
    __syncthreads();

    // ---------------- Phase 2: A[64x256] @ K[256x256] ----------------
    const int wm = wid >> 2;   // 0..1 : 32-row wave tile
    const int wn = wid & 3;    // 0..3 : 64-col wave tile

    f32x4 acc[2][4];
    #pragma unroll
    for (int mf = 0; mf < 2; ++mf)
        #pragma unroll
        for (int nf = 0; nf < 4; ++nf)
            acc[mf][nf] = (f32x4){0.f, 0.f, 0.f, 0.f};

    #pragma unroll
    for (int ks = 0; ks < 8; ++ks) {     // K = 256 = 8 * 32
        bf16x8 a[2], b[4];
        #pragma unroll
        for (int mf = 0; mf < 2; ++mf) {
            const int r  = wm * 32 + mf * 16 + c;
            const int ck = (ks * 4 + g) ^ (r & 7);
            a[mf] = *reinterpret_cast<const bf16x8*>(Asm + r * 512 + ck * 16);
        }
        #pragma unroll
        for (int nf = 0; nf < 4; ++nf) {
            const int nb = wn * 4 + nf;
            b[nf] = *reinterpret_cast<const bf16x8*>(
                btg + (size_t)((nb * 32 + ks * 4 + g) * 16 + c) * 8);  // lane-linear 1KB
        }
        #pragma unroll
        for (int mf = 0; mf < 2; ++mf)
            #pragma unroll
            for (int nf = 0; nf < 4; ++nf)
                acc[mf][nf] = __builtin_amdgcn_mfma_f32_16x16x32_bf16(
                    a[mf], b[nf], acc[mf][nf], 0, 0, 0);
    }

    // Epilogue: C/D layout col = lane&15, row = (lane>>4)*4 + reg. bias ok (Σw==1).
    #pragma unroll
    for (int mf = 0; mf < 2; ++mf) {
        const int row_l = wm * 32 + mf * 16 + g * 4;
        #pragma unroll
        for (int nf = 0; nf < 4; ++nf) {
            const int col = wn * 64 + nf * 16 + c;
            const float bb = bias[col];
            #pragma unroll
            for (int r = 0; r < 4; ++r) {
                const int rg = m0 + row_l + r;
                if (rg < V_N)
                    out[(size_t)rg * COUT_N + col] = acc[mf][nf][r] + bb;
            }
        }
    }
}

extern "C" void kernel_launch(void* const* d_in, const int* in_sizes, int n_in,
                              void* d_out, int out_size, void* d_ws, size_t ws_size,
                              hipStream_t stream) {
    const float* data     = (const float*)d_in[0];
    // d_in[1] = edge_src: implicit (vertex i owns edges [16i,16i+16)), unused
    const int*   edge_dst = (const int*)d_in[2];
    const float* edge_w   = (const float*)d_in[3];
    const float* kern     = (const float*)d_in[4];
    const float* bias     = (const float*)d_in[5];
    float*       out      = (float*)d_out;

    unsigned short* bt = (unsigned short*)d_ws;                          // 128KB
    unsigned short* db = (unsigned short*)d_ws + (size_t)K2_N * COUT_N;  // 12.8MB

    prep_bt_kernel<<<K2_N, COUT_N, 0, stream>>>(kern, bt);
    prep_data_kernel<<<(V_N * C_N / 8) / 256, 256, 0, stream>>>(data, db);

    const int nblk = (V_N + 63) / 64;   // 782
    dgc_fused_kernel<<<nblk, 512, 0, stream>>>(db, edge_dst, edge_w, bt, bias, out);
}